// Round 11
// baseline (375.436 us; speedup 1.0000x reference)
//
#include <hip/hip_runtime.h>

#define TT 512   // max sequence length T
#define NN 128   // number of tags N
#define NTHR 512 // 8 waves
#define SROW 192 // swizzled state row: 16 chunks x 12 floats (8 used + 4 pad)
#define SW8(i) (12 * ((i) >> 3) + ((i) & 7))
#define SWF 160  // fallback swizzle row (R5 layout)
#define SW(i) (20 * ((i) >> 4) + ((i) & 15))
#define TTS 130  // tt (T^T) row stride in floats: bank step 2, float2-aligned
#define BD  64   // (fallback kernel) backtrack chunk depth
#define MAXG 8   // (fallback kernel)

// Barrier WITHOUT vmcnt drain: LDS writes drained, global loads/stores stay
// in flight across the barrier.
#define STEP_BARRIER() asm volatile("s_waitcnt lgkmcnt(0)\n\ts_barrier" ::: "memory")

// DPP cross-lane (pure VALU, no LDS pipe)
template <int CTRL>
__device__ __forceinline__ int dpp_i(int x) {
    return __builtin_amdgcn_update_dpp(x, x, CTRL, 0xf, 0xf, true);
}
template <int CTRL>
__device__ __forceinline__ float dpp_f(float x) {
    union { float f; int i; } u; u.f = x;
    u.i = dpp_i<CTRL>(u.i);
    return u.f;
}
#define DPP_XOR1  0xB1   // quad_perm [1,0,3,2] : lane ^= 1
#define DPP_XOR2  0x4E   // quad_perm [2,3,0,1] : lane ^= 2
#define DPP_MIR7  0x141  // row_half_mirror (lane^=7): == ^4 after 1,2
#define DPP_MIR15 0x140  // row_mirror (lane^=15):     == ^8 after 1,2,4

// ---------------- FAST kernel: max-only forward + equality-ballot backtrack -
// One block per batch element, 512 threads. thread -> (j, c): j = tid>>4
// serves tags j, j+32, j+64, j+96; c = tid&15 owns i-range [8c, 8c+8).
// D=4 halves the per-step LDS read burst vs D=2 (16 wave-b128/step/CU): the
// burst drain is the step spine. Max-only forward (no index plumbing);
// value-only 4-stage DPP merge; state -> LDS (stride-12 swizzle, 2-way bank
// aliasing = free); pre-logit max M[t] -> ws. Backtrack: wave 0 recomputes
// candidates bitwise-identically; bp = first i with candidate == target via
// v_cmp_eq + ballot + ffs (exact first-occurrence).
__global__ __launch_bounds__(NTHR, 1)
void crf_viterbi_fast(const float* __restrict__ logits,
                      const float* __restrict__ trans,
                      const int* __restrict__ seqlen,
                      int* __restrict__ out,
                      float* __restrict__ ws) {
    __shared__ float stateBuf[2][SROW];
    __shared__ float tt[NN * TTS];  // tt[j*TTS+i] = trans[i*NN+j]
    __shared__ float redV[NN];
    __shared__ int   redI[NN];
    __shared__ int   tagBuf[TT];

    const int tid = threadIdx.x;
    const int j   = tid >> 4;   // 0..31; serves tags j, j+32, j+64, j+96
    const int c   = tid & 15;   // i-chunk
    const int i0  = c << 3;
    const int b   = blockIdx.x;
    const int L   = seqlen[b];  // in [1, TT]
    const int jx  = j + ((c & 3) << 5);  // tag whose x this lane loads (c<4 write)

    // Transition chunks: trd[k] = trans[i0+k][j + 32d]  (32 VGPRs)
    float tr0[8], tr1[8], tr2[8], tr3[8];
    #pragma unroll
    for (int k = 0; k < 8; ++k) {
        const float* tp = trans + (i0 + k) * NN + j;
        tr0[k] = tp[0];
        tr1[k] = tp[32];
        tr2[k] = tp[64];
        tr3[k] = tp[96];
    }

    // Transposed copy for backtrack. Stride TTS=130 (bank step 2 on fill).
    #pragma unroll
    for (int k = 0; k < (NN * NN) / NTHR; ++k) {
        int idx = k * NTHR + tid;
        tt[(idx & 127) * TTS + (idx >> 7)] = trans[idx];
    }

    const float* lrow = logits + (size_t)b * TT * NN;
    float* wsb = ws + (size_t)b * TT * NN;

    if (c < 4) {   // t = 0 init: LDS state = x[0]; ws row 0 = 0 (M[0] := 0)
        stateBuf[0][SW8(jx)] = lrow[jx];
        wsb[jx] = 0.0f;
    }
    __syncthreads();

    float xa = lrow[NN + jx];

    // 8-value max over (state + tr): max3-fused tree, order matches nothing —
    // max is order-invariant, value exact.
    #define TAGMAX(TR, OUT)                                                    \
    {                                                                          \
        float c0 = a0.x + TR[0], c1 = a0.y + TR[1];                            \
        float c2 = a0.z + TR[2], c3 = a0.w + TR[3];                            \
        float c4 = a1.x + TR[4], c5 = a1.y + TR[5];                            \
        float c6 = a1.z + TR[6], c7 = a1.w + TR[7];                            \
        float m0 = fmaxf(fmaxf(c0, c1), c2);                                   \
        float m1 = fmaxf(fmaxf(c3, c4), c5);                                   \
        float m2 = fmaxf(c6, c7);                                              \
        OUT = fmaxf(fmaxf(m0, m1), m2);                                        \
    }

    auto vstep = [&](const float* st, float* dst, int t) {
        int tn = (t + 1 < L) ? (t + 1) : (L - 1);
        float xnext = lrow[tn * NN + jx];

        const float* sp = st + 12 * c;
        float4 a0 = *(const float4*)(sp);
        float4 a1 = *(const float4*)(sp + 4);

        float bv0, bv1, bv2, bv3;
        TAGMAX(tr0, bv0)
        TAGMAX(tr1, bv1)
        TAGMAX(tr2, bv2)
        TAGMAX(tr3, bv3)

        // value-only 16-lane merge (exact: max is order-invariant)
        #define MSTAGE(CTRL)                                                   \
            bv0 = fmaxf(bv0, dpp_f<CTRL>(bv0));                                \
            bv1 = fmaxf(bv1, dpp_f<CTRL>(bv1));                                \
            bv2 = fmaxf(bv2, dpp_f<CTRL>(bv2));                                \
            bv3 = fmaxf(bv3, dpp_f<CTRL>(bv3));
        MSTAGE(DPP_XOR1)
        MSTAGE(DPP_XOR2)
        MSTAGE(DPP_MIR7)
        MSTAGE(DPP_MIR15)
        #undef MSTAGE

        if (c < 4) {   // lane c writes tag j + 32c
            float bv = (c == 0) ? bv0 : (c == 1) ? bv1 : (c == 2) ? bv2 : bv3;
            dst[SW8(jx)] = bv + xa;    // next step's state S[t]
            wsb[t * NN + jx] = bv;     // pre-logit max M[t] (for backtrack)
        }
        xa = xnext;
        STEP_BARRIER();   // lgkm-only: global stores/loads stay in flight
    };
    #undef TAGMAX

    int t = 1;
    for (; t + 1 < L; t += 2) {
        vstep(stateBuf[0], stateBuf[1], t);
        vstep(stateBuf[1], stateBuf[0], t + 1);
    }
    if (t < L) vstep(stateBuf[0], stateBuf[1], t);

    __syncthreads();   // full drain: ws stores complete & visible
    const int pf = (L - 1) & 1;

    // Final argmax over state (first-occurrence: min index on ties).
    if (tid < NN) { redV[tid] = stateBuf[pf][SW8(tid)]; redI[tid] = tid; }
    __syncthreads();
    #pragma unroll
    for (int off = 64; off >= 1; off >>= 1) {
        if (tid < off) {
            float va = redV[tid], vb = redV[tid + off];
            int   ia = redI[tid], ib = redI[tid + off];
            if (vb > va || (vb == va && ib < ia)) { redV[tid] = vb; redI[tid] = ib; }
        }
        __syncthreads();
    }

    // ---- Backtrack: wave 0, equality-ballot chase ----
    if (tid < 64) {
        const int lane = tid;
        int jc = redI[0];
        if (lane == 0) tagBuf[L - 1] = jc;

        auto wrow = [&](int r) -> float2 {   // M row (clamped rows unused)
            r = (r < 0) ? 0 : r;
            return *(const float2*)(wsb + r * NN + 2 * lane);
        };
        auto xrow = [&](int r) -> float2 {   // logits row
            r = (r < 0) ? 0 : r;
            return *(const float2*)(lrow + r * NN + 2 * lane);
        };
        auto extract2 = [&](float2 v, int idx) -> float {  // v[idx], idx uniform
            int sel = idx >> 1;
            int wx = __builtin_amdgcn_readlane(__float_as_int(v.x), sel);
            int wy = __builtin_amdgcn_readlane(__float_as_int(v.y), sel);
            return __int_as_float((idx & 1) ? wy : wx);
        };

        float2 rT = wrow(L - 1);
        float target = extract2(rT, jc);     // M[L-1][jc]

        // chase step t: m = M[t-1] row, xr = x[t-1] row. bp = first i with
        // (m[i]+xr[i])+T[i][jc] == target (bitwise-exact recompute -> exact
        // first-occurrence argmax, ties included).
        auto chase = [&](float2 m, float2 xr, int tc) {
            float2 tp = *(const float2*)(tt + jc * TTS + 2 * lane);
            float cA = (m.x + xr.x) + tp.x;
            float cB = (m.y + xr.y) + tp.y;
            unsigned long long mA = __ballot(cA == target);
            unsigned long long mB = __ballot(cB == target);
            int iA = mA ? (2 * (__ffsll(mA) - 1))     : (1 << 30);
            int iB = mB ? (2 * (__ffsll(mB) - 1) + 1) : (1 << 30);
            int bp = (iA < iB) ? iA : iB;
            if (lane == 0) tagBuf[tc - 1] = bp;
            target = extract2(m, bp);        // M[t-1][bp] for the next step
            jc = bp;
        };

        // 4-deep prefetch ring, statically unrolled
        float2 m0 = wrow(L - 2), x0 = xrow(L - 2);
        float2 m1 = wrow(L - 3), x1 = xrow(L - 3);
        float2 m2 = wrow(L - 4), x2 = xrow(L - 4);
        float2 m3 = wrow(L - 5), x3 = xrow(L - 5);
        int tb = L - 1;
        while (tb >= 4) {
            chase(m0, x0, tb);     m0 = wrow(tb - 5); x0 = xrow(tb - 5);
            chase(m1, x1, tb - 1); m1 = wrow(tb - 6); x1 = xrow(tb - 6);
            chase(m2, x2, tb - 2); m2 = wrow(tb - 7); x2 = xrow(tb - 7);
            chase(m3, x3, tb - 3); m3 = wrow(tb - 8); x3 = xrow(tb - 8);
            tb -= 4;
        }
        if (tb >= 1) chase(m0, x0, tb);
        if (tb >= 2) chase(m1, x1, tb - 1);
        if (tb >= 3) chase(m2, x2, tb - 2);
    }
    __syncthreads();

    // Coalesced output: tags for k < L, zeros for the masked tail.
    out[(size_t)b * TT + tid] = (tid < L) ? tagBuf[tid] : 0;
}

// ---------------- FALLBACK kernel: R5 (proven), used if ws too small --------
__global__ __launch_bounds__(NTHR, 1)
void crf_viterbi_fallback(const float* __restrict__ logits,
                          const float* __restrict__ trans,
                          const int* __restrict__ seqlen,
                          int* __restrict__ out) {
    __shared__ float stateBuf[2][SWF];
    __shared__ float redV[NN];
    __shared__ int   redI[NN];
    __shared__ int   tagBuf[TT];
    __shared__ int   entryTag[MAXG];
    __shared__ unsigned char bp[TT][NN];
    __shared__ unsigned char hist[MAXG][BD][NN];

    const int tid = threadIdx.x;
    const int j   = tid >> 3;
    const int c   = tid & 7;
    const int i0  = c << 4;
    const int b   = blockIdx.x;
    const int L   = seqlen[b];

    float tr0[16], tr1[16];
    #pragma unroll
    for (int k = 0; k < 16; ++k) {
        tr0[k] = trans[(i0 + k) * NN + j];
        tr1[k] = trans[(i0 + k) * NN + j + 64];
    }

    const float* lrow = logits + (size_t)b * TT * NN;
    if (c < 2) {
        int jj = j + (c << 6);
        stateBuf[0][SW(jj)] = lrow[jj];
    }
    __syncthreads();

    float xa0 = lrow[NN + j], xa1 = lrow[NN + j + 64];
    int p = 0;
    for (int t = 1; t < L; ++t) {
        int tn = (t + 1 < L) ? (t + 1) : (L - 1);
        const float* lp = lrow + tn * NN;
        float xb0 = lp[j];
        float xb1 = lp[j + 64];

        const float* st = stateBuf[p] + 20 * c;
        float4 a0 = *(const float4*)(st);
        float4 a1 = *(const float4*)(st + 4);
        float4 a2 = *(const float4*)(st + 8);
        float4 a3 = *(const float4*)(st + 12);

        float best0 = -__builtin_inff(), best1 = -__builtin_inff();
        int arg0 = 0, arg1 = 0;
        #define ELEM(S, K)                                                  \
        {                                                                   \
            float sc = (S) + tr0[K];                                        \
            bool g = sc > best0; best0 = g ? sc : best0; arg0 = g ? (K) : arg0; \
            float sd = (S) + tr1[K];                                        \
            bool h = sd > best1; best1 = h ? sd : best1; arg1 = h ? (K) : arg1; \
        }
        ELEM(a0.x, 0)  ELEM(a0.y, 1)  ELEM(a0.z, 2)  ELEM(a0.w, 3)
        ELEM(a1.x, 4)  ELEM(a1.y, 5)  ELEM(a1.z, 6)  ELEM(a1.w, 7)
        ELEM(a2.x, 8)  ELEM(a2.y, 9)  ELEM(a2.z, 10) ELEM(a2.w, 11)
        ELEM(a3.x, 12) ELEM(a3.y, 13) ELEM(a3.z, 14) ELEM(a3.w, 15)
        #undef ELEM

        float bv0 = best0, bv1 = best1;
        int   bi0 = i0 + arg0, bi1 = i0 + arg1;
        #define MERGE_STAGE(CTRL, LOWER)                                   \
        {                                                                  \
            float p0 = dpp_f<CTRL>(bv0); int q0 = dpp_i<CTRL>(bi0);        \
            float p1 = dpp_f<CTRL>(bv1); int q1 = dpp_i<CTRL>(bi1);        \
            bool lower = (LOWER);                                          \
            bool t0 = (p0 > bv0) || (p0 == bv0 && lower);                  \
            bool t1 = (p1 > bv1) || (p1 == bv1 && lower);                  \
            bv0 = t0 ? p0 : bv0; bi0 = t0 ? q0 : bi0;                      \
            bv1 = t1 ? p1 : bv1; bi1 = t1 ? q1 : bi1;                      \
        }
        MERGE_STAGE(DPP_XOR1, (c & 1) != 0)
        MERGE_STAGE(DPP_XOR2, (c & 2) != 0)
        MERGE_STAGE(DPP_MIR7, (c & 4) != 0)
        #undef MERGE_STAGE

        if (c < 2) {
            int   jj = j + (c << 6);
            float bv = c ? bv1 : bv0;
            int   bi = c ? bi1 : bi0;
            float xx = c ? xa1 : xa0;
            stateBuf[p ^ 1][SW(jj)] = bv + xx;
            bp[t][jj] = (unsigned char)bi;
        }
        xa0 = xb0; xa1 = xb1;
        __syncthreads();
        p ^= 1;
    }

    if (tid < NN) { redV[tid] = stateBuf[p][SW(tid)]; redI[tid] = tid; }
    __syncthreads();
    #pragma unroll
    for (int off = 64; off >= 1; off >>= 1) {
        if (tid < off) {
            float va = redV[tid], vb = redV[tid + off];
            int   ia = redI[tid], ib = redI[tid + off];
            if (vb > va || (vb == va && ib < ia)) { redV[tid] = vb; redI[tid] = ib; }
        }
        __syncthreads();
    }

    const int M = L - 1;
    const int G = (M + BD - 1) / BD;
    {
        int s  = tid & 127;
        int gA = tid >> 7;
        int gB = gA + 4;
        int thA = M - gA * BD, thB = M - gB * BD;
        int dA  = (gA < G) ? ((thA < BD) ? thA : BD) : 0;
        int dB  = (gB < G) ? ((thB < BD) ? thB : BD) : 0;
        int curA = s, curB = s;
        int maxd = (dA > dB) ? dA : dB;
        for (int d = 0; d < maxd; ++d) {
            if (d < dA) { curA = bp[thA - d][curA]; hist[gA][d][s] = (unsigned char)curA; }
            if (d < dB) { curB = bp[thB - d][curB]; hist[gB][d][s] = (unsigned char)curB; }
        }
    }
    __syncthreads();
    if (tid == 0) {
        int e = redI[0];
        tagBuf[L - 1] = e;
        for (int g = 0; g < G; ++g) {
            entryTag[g] = e;
            if (g + 1 < G) e = hist[g][BD - 1][e];
        }
    }
    __syncthreads();
    {
        int g = tid >> 6, d = tid & 63;
        if (g < MAXG && g < G) {
            int th  = M - g * BD;
            int dep = (th < BD) ? th : BD;
            if (d < dep) {
                int e = entryTag[g];
                tagBuf[th - 1 - d] = hist[g][d][e];
            }
        }
    }
    __syncthreads();
    out[(size_t)b * TT + tid] = (tid < L) ? tagBuf[tid] : 0;
}

extern "C" void kernel_launch(void* const* d_in, const int* in_sizes, int n_in,
                              void* d_out, int out_size, void* d_ws, size_t ws_size,
                              hipStream_t stream) {
    const float* logits = (const float*)d_in[0];
    const float* trans  = (const float*)d_in[1];
    const int*   seqlen = (const int*)d_in[2];
    int*         out    = (int*)d_out;
    const int B = in_sizes[2];  // 256
    const size_t need = (size_t)B * TT * NN * sizeof(float);  // 64 MiB
    if (ws_size >= need) {
        crf_viterbi_fast<<<B, NTHR, 0, stream>>>(logits, trans, seqlen, out,
                                                 (float*)d_ws);
    } else {
        crf_viterbi_fallback<<<B, NTHR, 0, stream>>>(logits, trans, seqlen, out);
    }
}

// Round 12
// 320.889 us; speedup vs baseline: 1.1700x; 1.1700x over previous
//
#include <hip/hip_runtime.h>

#define TT 512   // max sequence length T
#define NN 128   // number of tags N
#define NTHR 512 // 8 waves
#define SROW 160 // swizzled state row: 8 chunks x 20 floats (16 used + 4 pad)
#define SW(i) (20 * ((i) >> 4) + ((i) & 15))
#define TTS 130  // tt (T^T) row stride in floats: bank step 2, float2-aligned
#define BD  64   // (fallback kernel) backtrack chunk depth
#define MAXG 8   // (fallback kernel)

typedef float vf2 __attribute__((ext_vector_type(2)));
typedef float vf4 __attribute__((ext_vector_type(4)));

// Barrier WITHOUT vmcnt drain: LDS writes drained, global loads/stores stay
// in flight across the barrier.
#define STEP_BARRIER() asm volatile("s_waitcnt lgkmcnt(0)\n\ts_barrier" ::: "memory")

// Packed fp32 add: one instruction for two adds (full-rate on CDNA4).
__device__ __forceinline__ vf2 pk_add(vf2 a, vf2 b) {
    vf2 d;
    asm("v_pk_add_f32 %0, %1, %2" : "=v"(d) : "v"(a), "v"(b));
    return d;
}

// DPP cross-lane (pure VALU, no LDS pipe)
template <int CTRL>
__device__ __forceinline__ int dpp_i(int x) {
    return __builtin_amdgcn_update_dpp(x, x, CTRL, 0xf, 0xf, true);
}
template <int CTRL>
__device__ __forceinline__ float dpp_f(float x) {
    union { float f; int i; } u; u.f = x;
    u.i = dpp_i<CTRL>(u.i);
    return u.f;
}
#define DPP_XOR1 0xB1   // quad_perm [1,0,3,2] : lane ^= 1
#define DPP_XOR2 0x4E   // quad_perm [2,3,0,1] : lane ^= 2
#define DPP_MIR7 0x141  // row_half_mirror (lane^=7): == ^4 after 1,2

// ---------------- FAST kernel: max-only forward + equality-ballot backtrack -
// R10 structure (champion): 512 threads, thread (j,c): j = tid>>3 serves tags
// j, j+64; c = tid&7 owns i-range [16c,16c+16). Slimmed issue stream:
// v_pk_add_f32 (2 adds/instr), hoisted pointers advanced by constants, no
// per-step clamp (tail restructure). Max-only forward, value-only DPP merge,
// state -> LDS stride-20 swizzle; pre-logit max M[t] -> ws. Backtrack: wave 0
// equality-ballot chase (bitwise-exact recompute, first-occurrence exact).
__global__ __launch_bounds__(NTHR, 1)
void crf_viterbi_fast(const float* __restrict__ logits,
                      const float* __restrict__ trans,
                      const int* __restrict__ seqlen,
                      int* __restrict__ out,
                      float* __restrict__ ws) {
    __shared__ float stateBuf[2][SROW];
    __shared__ float tt[NN * TTS];  // tt[j*TTS+i] = trans[i*NN+j]
    __shared__ float redV[NN];
    __shared__ int   redI[NN];
    __shared__ int   tagBuf[TT];

    const int tid = threadIdx.x;
    const int j   = tid >> 3;   // 0..63 (serves j and j+64)
    const int c   = tid & 7;    // i-chunk
    const int i0  = c << 4;
    const int b   = blockIdx.x;
    const int L   = seqlen[b];  // in [1, TT]
    const int jx  = j + ((c & 1) << 6);

    // Transition chunks as vf2 pairs: tr0[q] = {T[i0+2q][j], T[i0+2q+1][j]}
    vf2 tr0[8], tr1[8];
    #pragma unroll
    for (int q = 0; q < 8; ++q) {
        const float* ta = trans + (i0 + 2 * q) * NN + j;
        const float* tb = trans + (i0 + 2 * q + 1) * NN + j;
        tr0[q] = (vf2){ta[0], tb[0]};
        tr1[q] = (vf2){ta[64], tb[64]};
    }

    // Transposed copy for backtrack. Stride TTS=130 (bank step 2 on fill).
    #pragma unroll
    for (int k = 0; k < (NN * NN) / NTHR; ++k) {
        int idx = k * NTHR + tid;
        tt[(idx & 127) * TTS + (idx >> 7)] = trans[idx];
    }

    const float* lrow = logits + (size_t)b * TT * NN;
    float* wsb = ws + (size_t)b * TT * NN;

    if (c < 2) {   // t = 0 init: LDS state = x[0]; ws row 0 = 0 (M[0] := 0)
        stateBuf[0][SW(jx)] = lrow[jx];
        wsb[jx] = 0.0f;
    }
    __syncthreads();

    // Hoisted pointers, advanced by constants inside the loop.
    float xa = lrow[NN + jx];            // x row 1 (t=1's logit)
    const float* xp    = lrow + 2 * NN;  // prefetch ptr: row t+1 (starts at 2)
    float*       wsrow = wsb + NN;       // M row t (starts at 1)
    const float* sp0 = &stateBuf[0][20 * c];
    const float* sp1 = &stateBuf[1][20 * c];
    float*       wp0 = &stateBuf[0][SW(jx)];
    float*       wp1 = &stateBuf[1][SW(jx)];

    // 16-value max over (state + tr) with pk_add: 8 pk_add + 8 max/max3.
    #define TAGMAX(TR, OUT)                                                    \
    {                                                                          \
        vf2 p0 = pk_add(a0.lo, TR[0]); vf2 p1 = pk_add(a0.hi, TR[1]);          \
        vf2 p2 = pk_add(a1.lo, TR[2]); vf2 p3 = pk_add(a1.hi, TR[3]);          \
        vf2 p4 = pk_add(a2.lo, TR[4]); vf2 p5 = pk_add(a2.hi, TR[5]);          \
        vf2 p6 = pk_add(a3.lo, TR[6]); vf2 p7 = pk_add(a3.hi, TR[7]);          \
        float m0 = fmaxf(fmaxf(p0.x, p0.y), p1.x);                             \
        float m1 = fmaxf(fmaxf(p1.y, p2.x), p2.y);                             \
        float m2 = fmaxf(fmaxf(p3.x, p3.y), p4.x);                             \
        float m3 = fmaxf(fmaxf(p4.y, p5.x), p5.y);                             \
        float m4 = fmaxf(fmaxf(p6.x, p6.y), p7.x);                             \
        OUT = fmaxf(fmaxf(fmaxf(m0, m1), m2), fmaxf(fmaxf(m3, m4), p7.y));     \
    }

    auto vstep = [&](const float* sp, float* wp, bool pre) {
        float xnext = 0.0f;
        if (pre) xnext = xp[jx];         // row t+1, always in-bounds when pre

        vf4 a0 = *(const vf4*)(sp);
        vf4 a1 = *(const vf4*)(sp + 4);
        vf4 a2 = *(const vf4*)(sp + 8);
        vf4 a3 = *(const vf4*)(sp + 12);

        float bv0, bv1;
        TAGMAX(tr0, bv0)
        TAGMAX(tr1, bv1)

        // value-only octet merge (max is order-invariant -> exact)
        bv0 = fmaxf(bv0, dpp_f<DPP_XOR1>(bv0)); bv1 = fmaxf(bv1, dpp_f<DPP_XOR1>(bv1));
        bv0 = fmaxf(bv0, dpp_f<DPP_XOR2>(bv0)); bv1 = fmaxf(bv1, dpp_f<DPP_XOR2>(bv1));
        bv0 = fmaxf(bv0, dpp_f<DPP_MIR7>(bv0)); bv1 = fmaxf(bv1, dpp_f<DPP_MIR7>(bv1));

        if (c < 2) {   // c=0 writes tag j, c=1 writes tag j+64
            float bv = c ? bv1 : bv0;
            *wp = bv + xa;               // next step's state S[t]
            wsrow[jx] = bv;              // pre-logit max M[t] (for backtrack)
        }
        xa = xnext;
        xp += NN;
        wsrow += NN;
        STEP_BARRIER();   // lgkm-only: global stores/loads stay in flight
    };
    #undef TAGMAX

    // Steps t = 1 .. L-1; prefetch is unconditional except on the final step.
    int t = 1;
    for (; t + 2 < L; t += 2) {
        vstep(sp0, wp1, true);
        vstep(sp1, wp0, true);
    }
    if (t + 1 < L) {            // exactly 2 steps remain
        vstep(sp0, wp1, true);
        vstep(sp1, wp0, false);
    } else if (t < L) {         // exactly 1 step remains
        vstep(sp0, wp1, false);
    }

    __syncthreads();   // full drain: ws stores complete & visible
    const int pf = (L - 1) & 1;

    // Final argmax over state (first-occurrence: min index on ties).
    if (tid < NN) { redV[tid] = stateBuf[pf][SW(tid)]; redI[tid] = tid; }
    __syncthreads();
    #pragma unroll
    for (int off = 64; off >= 1; off >>= 1) {
        if (tid < off) {
            float va = redV[tid], vb = redV[tid + off];
            int   ia = redI[tid], ib = redI[tid + off];
            if (vb > va || (vb == va && ib < ia)) { redV[tid] = vb; redI[tid] = ib; }
        }
        __syncthreads();
    }

    // ---- Backtrack: wave 0, equality-ballot chase ----
    if (tid < 64) {
        const int lane = tid;
        int jc = redI[0];
        if (lane == 0) tagBuf[L - 1] = jc;

        auto wrow = [&](int r) -> float2 {   // M row (clamped rows unused)
            r = (r < 0) ? 0 : r;
            return *(const float2*)(wsb + r * NN + 2 * lane);
        };
        auto xrow = [&](int r) -> float2 {   // logits row
            r = (r < 0) ? 0 : r;
            return *(const float2*)(lrow + r * NN + 2 * lane);
        };
        auto extract2 = [&](float2 v, int idx) -> float {  // v[idx], idx uniform
            int sel = idx >> 1;
            int wx = __builtin_amdgcn_readlane(__float_as_int(v.x), sel);
            int wy = __builtin_amdgcn_readlane(__float_as_int(v.y), sel);
            return __int_as_float((idx & 1) ? wy : wx);
        };

        float2 rT = wrow(L - 1);
        float target = extract2(rT, jc);     // M[L-1][jc]

        // chase step t: m = M[t-1] row, xr = x[t-1] row. bp = first i with
        // (m[i]+xr[i])+T[i][jc] == target (bitwise-exact recompute -> exact
        // first-occurrence argmax, ties included).
        auto chase = [&](float2 m, float2 xr, int tc) {
            float2 tp = *(const float2*)(tt + jc * TTS + 2 * lane);
            float cA = (m.x + xr.x) + tp.x;
            float cB = (m.y + xr.y) + tp.y;
            unsigned long long mA = __ballot(cA == target);
            unsigned long long mB = __ballot(cB == target);
            int iA = mA ? (2 * (__ffsll(mA) - 1))     : (1 << 30);
            int iB = mB ? (2 * (__ffsll(mB) - 1) + 1) : (1 << 30);
            int bp = (iA < iB) ? iA : iB;
            if (lane == 0) tagBuf[tc - 1] = bp;
            target = extract2(m, bp);        // M[t-1][bp] for the next step
            jc = bp;
        };

        // 4-deep prefetch ring, statically unrolled
        float2 m0 = wrow(L - 2), x0 = xrow(L - 2);
        float2 m1 = wrow(L - 3), x1 = xrow(L - 3);
        float2 m2 = wrow(L - 4), x2 = xrow(L - 4);
        float2 m3 = wrow(L - 5), x3 = xrow(L - 5);
        int tb = L - 1;
        while (tb >= 4) {
            chase(m0, x0, tb);     m0 = wrow(tb - 5); x0 = xrow(tb - 5);
            chase(m1, x1, tb - 1); m1 = wrow(tb - 6); x1 = xrow(tb - 6);
            chase(m2, x2, tb - 2); m2 = wrow(tb - 7); x2 = xrow(tb - 7);
            chase(m3, x3, tb - 3); m3 = wrow(tb - 8); x3 = xrow(tb - 8);
            tb -= 4;
        }
        if (tb >= 1) chase(m0, x0, tb);
        if (tb >= 2) chase(m1, x1, tb - 1);
        if (tb >= 3) chase(m2, x2, tb - 2);
    }
    __syncthreads();

    // Coalesced output: tags for k < L, zeros for the masked tail.
    out[(size_t)b * TT + tid] = (tid < L) ? tagBuf[tid] : 0;
}

// ---------------- FALLBACK kernel: R5 (proven), used if ws too small --------
__global__ __launch_bounds__(NTHR, 1)
void crf_viterbi_fallback(const float* __restrict__ logits,
                          const float* __restrict__ trans,
                          const int* __restrict__ seqlen,
                          int* __restrict__ out) {
    __shared__ float stateBuf[2][SROW];
    __shared__ float redV[NN];
    __shared__ int   redI[NN];
    __shared__ int   tagBuf[TT];
    __shared__ int   entryTag[MAXG];
    __shared__ unsigned char bp[TT][NN];
    __shared__ unsigned char hist[MAXG][BD][NN];

    const int tid = threadIdx.x;
    const int j   = tid >> 3;
    const int c   = tid & 7;
    const int i0  = c << 4;
    const int b   = blockIdx.x;
    const int L   = seqlen[b];

    float tr0[16], tr1[16];
    #pragma unroll
    for (int k = 0; k < 16; ++k) {
        tr0[k] = trans[(i0 + k) * NN + j];
        tr1[k] = trans[(i0 + k) * NN + j + 64];
    }

    const float* lrow = logits + (size_t)b * TT * NN;
    if (c < 2) {
        int jj = j + (c << 6);
        stateBuf[0][SW(jj)] = lrow[jj];
    }
    __syncthreads();

    float xa0 = lrow[NN + j], xa1 = lrow[NN + j + 64];
    int p = 0;
    for (int t = 1; t < L; ++t) {
        int tn = (t + 1 < L) ? (t + 1) : (L - 1);
        const float* lp = lrow + tn * NN;
        float xb0 = lp[j];
        float xb1 = lp[j + 64];

        const float* st = stateBuf[p] + 20 * c;
        float4 a0 = *(const float4*)(st);
        float4 a1 = *(const float4*)(st + 4);
        float4 a2 = *(const float4*)(st + 8);
        float4 a3 = *(const float4*)(st + 12);

        float best0 = -__builtin_inff(), best1 = -__builtin_inff();
        int arg0 = 0, arg1 = 0;
        #define ELEM(S, K)                                                  \
        {                                                                   \
            float sc = (S) + tr0[K];                                        \
            bool g = sc > best0; best0 = g ? sc : best0; arg0 = g ? (K) : arg0; \
            float sd = (S) + tr1[K];                                        \
            bool h = sd > best1; best1 = h ? sd : best1; arg1 = h ? (K) : arg1; \
        }
        ELEM(a0.x, 0)  ELEM(a0.y, 1)  ELEM(a0.z, 2)  ELEM(a0.w, 3)
        ELEM(a1.x, 4)  ELEM(a1.y, 5)  ELEM(a1.z, 6)  ELEM(a1.w, 7)
        ELEM(a2.x, 8)  ELEM(a2.y, 9)  ELEM(a2.z, 10) ELEM(a2.w, 11)
        ELEM(a3.x, 12) ELEM(a3.y, 13) ELEM(a3.z, 14) ELEM(a3.w, 15)
        #undef ELEM

        float bv0 = best0, bv1 = best1;
        int   bi0 = i0 + arg0, bi1 = i0 + arg1;
        #define MERGE_STAGE(CTRL, LOWER)                                   \
        {                                                                  \
            float p0 = dpp_f<CTRL>(bv0); int q0 = dpp_i<CTRL>(bi0);        \
            float p1 = dpp_f<CTRL>(bv1); int q1 = dpp_i<CTRL>(bi1);        \
            bool lower = (LOWER);                                          \
            bool t0 = (p0 > bv0) || (p0 == bv0 && lower);                  \
            bool t1 = (p1 > bv1) || (p1 == bv1 && lower);                  \
            bv0 = t0 ? p0 : bv0; bi0 = t0 ? q0 : bi0;                      \
            bv1 = t1 ? p1 : bv1; bi1 = t1 ? q1 : bi1;                      \
        }
        MERGE_STAGE(DPP_XOR1, (c & 1) != 0)
        MERGE_STAGE(DPP_XOR2, (c & 2) != 0)
        MERGE_STAGE(DPP_MIR7, (c & 4) != 0)
        #undef MERGE_STAGE

        if (c < 2) {
            int   jj = j + (c << 6);
            float bv = c ? bv1 : bv0;
            int   bi = c ? bi1 : bi0;
            float xx = c ? xa1 : xa0;
            stateBuf[p ^ 1][SW(jj)] = bv + xx;
            bp[t][jj] = (unsigned char)bi;
        }
        xa0 = xb0; xa1 = xb1;
        __syncthreads();
        p ^= 1;
    }

    if (tid < NN) { redV[tid] = stateBuf[p][SW(tid)]; redI[tid] = tid; }
    __syncthreads();
    #pragma unroll
    for (int off = 64; off >= 1; off >>= 1) {
        if (tid < off) {
            float va = redV[tid], vb = redV[tid + off];
            int   ia = redI[tid], ib = redI[tid + off];
            if (vb > va || (vb == va && ib < ia)) { redV[tid] = vb; redI[tid] = ib; }
        }
        __syncthreads();
    }

    const int M = L - 1;
    const int G = (M + BD - 1) / BD;
    {
        int s  = tid & 127;
        int gA = tid >> 7;
        int gB = gA + 4;
        int thA = M - gA * BD, thB = M - gB * BD;
        int dA  = (gA < G) ? ((thA < BD) ? thA : BD) : 0;
        int dB  = (gB < G) ? ((thB < BD) ? thB : BD) : 0;
        int curA = s, curB = s;
        int maxd = (dA > dB) ? dA : dB;
        for (int d = 0; d < maxd; ++d) {
            if (d < dA) { curA = bp[thA - d][curA]; hist[gA][d][s] = (unsigned char)curA; }
            if (d < dB) { curB = bp[thB - d][curB]; hist[gB][d][s] = (unsigned char)curB; }
        }
    }
    __syncthreads();
    if (tid == 0) {
        int e = redI[0];
        tagBuf[L - 1] = e;
        for (int g = 0; g < G; ++g) {
            entryTag[g] = e;
            if (g + 1 < G) e = hist[g][BD - 1][e];
        }
    }
    __syncthreads();
    {
        int g = tid >> 6, d = tid & 63;
        if (g < MAXG && g < G) {
            int th  = M - g * BD;
            int dep = (th < BD) ? th : BD;
            if (d < dep) {
                int e = entryTag[g];
                tagBuf[th - 1 - d] = hist[g][d][e];
            }
        }
    }
    __syncthreads();
    out[(size_t)b * TT + tid] = (tid < L) ? tagBuf[tid] : 0;
}

extern "C" void kernel_launch(void* const* d_in, const int* in_sizes, int n_in,
                              void* d_out, int out_size, void* d_ws, size_t ws_size,
                              hipStream_t stream) {
    const float* logits = (const float*)d_in[0];
    const float* trans  = (const float*)d_in[1];
    const int*   seqlen = (const int*)d_in[2];
    int*         out    = (int*)d_out;
    const int B = in_sizes[2];  // 256
    const size_t need = (size_t)B * TT * NN * sizeof(float);  // 64 MiB
    if (ws_size >= need) {
        crf_viterbi_fast<<<B, NTHR, 0, stream>>>(logits, trans, seqlen, out,
                                                 (float*)d_ws);
    } else {
        crf_viterbi_fallback<<<B, NTHR, 0, stream>>>(logits, trans, seqlen, out);
    }
}